// Round 1
// baseline (571.619 us; speedup 1.0000x reference)
//
#include <hip/hip_runtime.h>
#include <hip/hip_bf16.h>

// ModulatedConv2d: B=16, Cin=Cout=512, H=W=64, 3x3, pad 1.
// out[b,o] = demod[b,o]*CONV_SCALE * conv2d(s[b,:]*x[b], weight)   (weights shared across batch)

constexpr float CONV_SCALE = 0.014731391274719738f;  // 1/sqrt(512*9)
constexpr float MOD_SCALE  = 0.04419417382415922f;   // 1/sqrt(512)

typedef short  bf16x8 __attribute__((ext_vector_type(8)));
typedef float  f32x4  __attribute__((ext_vector_type(4)));

__device__ __forceinline__ unsigned short f2bf(float f) {
  unsigned u = __float_as_uint(f);
  u += 0x7fffu + ((u >> 16) & 1u);           // round-to-nearest-even
  return (unsigned short)(u >> 16);
}

__device__ __forceinline__ void async16(const void* g, void* l) {
  __builtin_amdgcn_global_load_lds((const __attribute__((address_space(1))) unsigned int*)g,
                                   (__attribute__((address_space(3))) unsigned int*)l,
                                   16, 0, 0);
}

// ---------- kernel 1: s[b,i] = style[b,:] . mod_weight[i,:] * MOD_SCALE + mod_bias[i] ----------
__global__ void k_style(const float* __restrict__ style, const float* __restrict__ mw,
                        const float* __restrict__ mb, float* __restrict__ s) {
  int t = blockIdx.x * 256 + threadIdx.x;    // 8192 threads
  int b = t & 15, i = t >> 4;
  const float* st = style + b * 512;
  const float* wr = mw + i * 512;
  float acc = 0.f;
  for (int j = 0; j < 512; ++j) acc += st[j] * wr[j];
  s[b * 512 + i] = acc * MOD_SCALE + mb[i];
}

// ---------- kernel 2: wsq[o,i] = sum_taps w^2 ; wt[kh][kw][o][ic] = bf16(w) ----------
__global__ void k_prepw(const float* __restrict__ w, float* __restrict__ wsq,
                        unsigned short* __restrict__ wt) {
  int t = blockIdx.x * 256 + threadIdx.x;    // 262144 threads
  int ic = t & 511, o = t >> 9;
  const float* wp = w + (size_t)(o * 512 + ic) * 9;
  float ssq = 0.f;
#pragma unroll
  for (int tap = 0; tap < 9; ++tap) {
    float v = wp[tap];
    ssq += v * v;
    wt[((size_t)tap * 512 + o) * 512 + ic] = f2bf(v);
  }
  wsq[o * 512 + ic] = ssq;
}

// ---------- kernel 3: dscale[b,o] = rsqrt(CS^2 * sum_i wsq[o,i]*s[b,i]^2 + 1e-8) * CS ----------
__global__ void k_dscale(const float* __restrict__ s, const float* __restrict__ wsq,
                         float* __restrict__ dscale) {
  int t = blockIdx.x * 256 + threadIdx.x;    // 8192 threads
  int b = t & 15, o = t >> 4;
  const float* sq = wsq + o * 512;
  const float* sb = s + b * 512;
  float acc = 0.f;
  for (int i = 0; i < 512; ++i) { float si = sb[i]; acc += sq[i] * si * si; }
  float d = rsqrtf(CONV_SCALE * CONV_SCALE * acc + 1e-8f);
  dscale[b * 512 + o] = d * CONV_SCALE;
}

// ---------- kernel 4: xt[b][h][w][ic] = bf16(x[b][ic][h][w] * s[b][ic])  (NCHW->NHWC) ----------
__global__ void k_xt(const float* __restrict__ x, const float* __restrict__ s,
                     unsigned short* __restrict__ xt) {
  __shared__ float T[64][65];
  int h = blockIdx.x, b = blockIdx.y;
  const float* xp = x + (size_t)b * 512 * 4096 + h * 64;
  unsigned short* xo = xt + ((size_t)(b * 64 + h) * 64) * 512;
  int t = threadIdx.x;
  int wcol = t & 63, icl0 = t >> 6;
  for (int ic0 = 0; ic0 < 512; ic0 += 64) {
#pragma unroll
    for (int k = 0; k < 16; ++k) {
      int icl = icl0 + k * 4;
      int ic = ic0 + icl;
      T[icl][wcol] = xp[(size_t)ic * 4096 + wcol] * s[b * 512 + ic];
    }
    __syncthreads();
#pragma unroll
    for (int c = t; c < 512; c += 256) {   // 64 w * 8 groups of 8 ch
      int wv = c >> 3, ig = (c & 7) * 8;
      unsigned p0 = (unsigned)f2bf(T[ig + 0][wv]) | ((unsigned)f2bf(T[ig + 1][wv]) << 16);
      unsigned p1 = (unsigned)f2bf(T[ig + 2][wv]) | ((unsigned)f2bf(T[ig + 3][wv]) << 16);
      unsigned p2 = (unsigned)f2bf(T[ig + 4][wv]) | ((unsigned)f2bf(T[ig + 5][wv]) << 16);
      unsigned p3 = (unsigned)f2bf(T[ig + 6][wv]) | ((unsigned)f2bf(T[ig + 7][wv]) << 16);
      uint4 pk = {p0, p1, p2, p3};
      *(uint4*)&xo[(size_t)wv * 512 + ic0 + ig] = pk;
    }
    __syncthreads();
  }
}

// ---------- kernel 5: the conv (implicit GEMM, MFMA bf16) ----------
// grid (32 h-tiles, 4 o-tiles, 16 b); block 256 = 4 waves (2x2).
// Tile: 128 o  x  (2 rows x 64 cols).  Wave: 64 o x 1 row (64 cols), 4x4 accs of 16x16.
__global__ __launch_bounds__(256, 3)
void k_conv(const unsigned short* __restrict__ xt, const unsigned short* __restrict__ wt,
            const float* __restrict__ dscale, float* __restrict__ out) {
  __shared__ short Xs[4 * 66 * 32];   // [row][col(pad+64+pad)][ic32]
  __shared__ short Ws[3 * 128 * 32];  // [kw][o128][ic32]

  const int b  = blockIdx.z;
  const int o0 = blockIdx.y * 128;
  const int h0 = blockIdx.x * 2;
  const int t = threadIdx.x;
  const int wave = t >> 6, lane = t & 63;
  const int q = lane >> 4, l16 = lane & 15;
  const int wm = wave >> 1, wn = wave & 1;

  f32x4 acc[4][4];
#pragma unroll
  for (int i = 0; i < 4; ++i)
#pragma unroll
    for (int j = 0; j < 4; ++j) acc[i][j] = (f32x4){0.f, 0.f, 0.f, 0.f};

  // zero the halo columns (col 0 and 65) once; never overwritten by staging
  {
    int r = t >> 6, c = (t >> 5) & 1, ch = t & 31;
    Xs[(r * 66 + c * 65) * 32 + ch] = 0;
  }

  // X staging: wave = row r in [0,4), global row hg = h0-1+wave
  const int hg = h0 - 1 + wave;
  const bool valid = (hg >= 0) && (hg < 64);
  const unsigned short* xrow =
      xt + ((size_t)(b * 64 + (valid ? hg : 0)) * 64) * 512 + (lane >> 2) * 512 + (lane & 3) * 8;

  for (int ic0 = 0; ic0 < 512; ic0 += 32) {
    __syncthreads();
    // ---- stage X: 4 rows x 64 cols x 32 ch (16 KB); 4 x 1KB per wave
    if (valid) {
#pragma unroll
      for (int j = 0; j < 4; ++j)
        async16(xrow + (size_t)j * 16 * 512 + ic0, &Xs[(wave * 66 + 1 + j * 16) * 32]);
    } else {
#pragma unroll
      for (int j = 0; j < 4; ++j)
        *(int4*)&Xs[(wave * 66 + 1 + j * 16) * 32 + lane * 8] = (int4){0, 0, 0, 0};
    }
#pragma unroll
    for (int kh = 0; kh < 3; ++kh) {
      if (kh) __syncthreads();
      // ---- stage W for this kh: 3 kw x 128 o x 32 ic (24 KB); 6 x 1KB per wave
#pragma unroll
      for (int j = 0; j < 6; ++j) {
        int ci = wave * 6 + j;
        int kw = ci >> 3, oo = ((ci & 7) << 4) + (lane >> 2);
        async16(wt + (((size_t)(kh * 3 + kw) * 512 + o0 + oo) * 512 + ic0 + (lane & 3) * 8),
                &Ws[ci * 512]);
      }
      __syncthreads();
      // ---- compute
      const short* xbase = &Xs[(wn + kh) * 66 * 32 + q * 8];
#pragma unroll
      for (int kw = 0; kw < 3; ++kw) {
        bf16x8 af[4], bfr[4];
#pragma unroll
        for (int mi = 0; mi < 4; ++mi)
          af[mi] = *(const bf16x8*)&Ws[(kw * 128 + wm * 64 + mi * 16 + l16) * 32 + q * 8];
#pragma unroll
        for (int ni = 0; ni < 4; ++ni)
          bfr[ni] = *(const bf16x8*)&xbase[(ni * 16 + l16 + kw) * 32];
#pragma unroll
        for (int mi = 0; mi < 4; ++mi)
#pragma unroll
          for (int ni = 0; ni < 4; ++ni)
            acc[mi][ni] = __builtin_amdgcn_mfma_f32_16x16x32_bf16(af[mi], bfr[ni], acc[mi][ni], 0, 0, 0);
      }
    }
  }

  // ---- epilogue: D[row=q*4+r][col=l16] per 16x16 frag; scale by dscale[b,o]
  const int h = h0 + wn;
  float* orow = out + ((size_t)(b * 512 + o0 + wm * 64) * 64 + h) * 64;
#pragma unroll
  for (int mi = 0; mi < 4; ++mi) {
#pragma unroll
    for (int r = 0; r < 4; ++r) {
      int o_l = mi * 16 + q * 4 + r;
      float ds = dscale[b * 512 + o0 + wm * 64 + o_l];
#pragma unroll
      for (int ni = 0; ni < 4; ++ni)
        orow[(size_t)o_l * 4096 + ni * 16 + l16] = acc[mi][ni][r] * ds;
    }
  }
}

extern "C" void kernel_launch(void* const* d_in, const int* in_sizes, int n_in,
                              void* d_out, int out_size, void* d_ws, size_t ws_size,
                              hipStream_t stream) {
  const float* x      = (const float*)d_in[0];  // (16,512,64,64)
  const float* style  = (const float*)d_in[1];  // (16,512)
  const float* weight = (const float*)d_in[2];  // (1,512,512,3,3)
  const float* mw     = (const float*)d_in[3];  // (512,512)
  const float* mb     = (const float*)d_in[4];  // (512,)
  float* out = (float*)d_out;

  // workspace layout
  float* s      = (float*)d_ws;                       // 8192 f32
  float* dscale = s + 8192;                           // 8192 f32
  float* wsq    = dscale + 8192;                      // 262144 f32
  unsigned short* wt = (unsigned short*)(wsq + 262144);  // 9*512*512 bf16 = 4.5 MiB
  unsigned short* xt = wt + 9 * 512 * 512;            // 16*64*64*512 bf16 = 64 MiB

  k_style<<<32, 256, 0, stream>>>(style, mw, mb, s);
  k_prepw<<<1024, 256, 0, stream>>>(weight, wsq, wt);
  k_dscale<<<32, 256, 0, stream>>>(s, wsq, dscale);
  k_xt<<<dim3(64, 16), 256, 0, stream>>>(x, s, xt);
  k_conv<<<dim3(32, 4, 16), 256, 0, stream>>>(xt, wt, dscale, out);
}

// Round 2
// 516.087 us; speedup vs baseline: 1.1076x; 1.1076x over previous
//
#include <hip/hip_runtime.h>
#include <hip/hip_bf16.h>

// ModulatedConv2d: B=16, Cin=Cout=512, H=W=64, 3x3, pad 1.
// out[b,o] = dscale[b,o] * conv2d(s[b,:]*x[b], weight)   (weights shared across batch)

constexpr float CONV_SCALE = 0.014731391274719738f;  // 1/sqrt(512*9)
constexpr float MOD_SCALE  = 0.04419417382415922f;   // 1/sqrt(512)

typedef short  bf16x8 __attribute__((ext_vector_type(8)));
typedef float  f32x4  __attribute__((ext_vector_type(4)));

__device__ __forceinline__ unsigned short f2bf(float f) {
  unsigned u = __float_as_uint(f);
  u += 0x7fffu + ((u >> 16) & 1u);           // round-to-nearest-even
  return (unsigned short)(u >> 16);
}

__device__ __forceinline__ void async16(const void* g, void* l) {
  __builtin_amdgcn_global_load_lds((const __attribute__((address_space(1))) unsigned int*)g,
                                   (__attribute__((address_space(3))) unsigned int*)l,
                                   16, 0, 0);
}

// ---------- kernel 1: s[b,i] = style[b,:] . mod_weight[i,:] * MOD_SCALE + mod_bias[i] ----------
__global__ void k_style(const float* __restrict__ style, const float* __restrict__ mw,
                        const float* __restrict__ mb, float* __restrict__ s) {
  int t = blockIdx.x * 256 + threadIdx.x;    // 8192 threads
  int b = t & 15, i = t >> 4;
  const float4* st = (const float4*)(style + b * 512);
  const float4* wr = (const float4*)(mw + i * 512);
  float acc = 0.f;
#pragma unroll 8
  for (int j = 0; j < 128; ++j) {
    float4 a = st[j], w4 = wr[j];
    acc += a.x * w4.x + a.y * w4.y + a.z * w4.z + a.w * w4.w;
  }
  s[b * 512 + i] = acc * MOD_SCALE + mb[i];
}

// ---------- kernel 2: wsq[o,i] = sum_taps w^2 ; wt[kh][kw][o][ic] = bf16(w) ----------
// coalesced: block stages 256 pairs * 9 floats = 9216 B via float4, then gathers from LDS
__global__ void k_prepw(const float* __restrict__ w, float* __restrict__ wsq,
                        unsigned short* __restrict__ wt) {
  __shared__ float Wl[2304];
  int t = threadIdx.x;
  size_t base = (size_t)blockIdx.x * 2304;
#pragma unroll
  for (int k = 0; k < 3; ++k) {
    int idx = t + k * 256;
    if (idx < 576) ((float4*)Wl)[idx] = ((const float4*)(w + base))[idx];
  }
  __syncthreads();
  int g = blockIdx.x * 256 + t;
  int ic = g & 511, o = g >> 9;
  float ssq = 0.f;
#pragma unroll
  for (int tap = 0; tap < 9; ++tap) {
    float v = Wl[t * 9 + tap];
    ssq += v * v;
    wt[((size_t)tap * 512 + o) * 512 + ic] = f2bf(v);
  }
  wsq[o * 512 + ic] = ssq;
}

// ---------- kernel 3: dscale[b,o] = rsqrt(CS^2 * sum_i wsq[o,i]*s[b,i]^2 + 1e-8) * CS ----------
__global__ void k_dscale(const float* __restrict__ s, const float* __restrict__ wsq,
                         float* __restrict__ dscale) {
  int t = blockIdx.x * 256 + threadIdx.x;    // 8192 threads
  int b = t & 15, o = t >> 4;
  const float4* sq = (const float4*)(wsq + o * 512);
  const float4* sb = (const float4*)(s + b * 512);
  float acc = 0.f;
#pragma unroll 8
  for (int j = 0; j < 128; ++j) {
    float4 q4 = sq[j], s4 = sb[j];
    acc += q4.x * s4.x * s4.x + q4.y * s4.y * s4.y + q4.z * s4.z * s4.z + q4.w * s4.w * s4.w;
  }
  float d = rsqrtf(CONV_SCALE * CONV_SCALE * acc + 1e-8f);
  dscale[b * 512 + o] = d * CONV_SCALE;
}

// ---------- kernel 4: xt[b][h][w][ic] = bf16(x[b][ic][h][w] * s[b][ic])  (NCHW->NHWC) ----------
__global__ void k_xt(const float* __restrict__ x, const float* __restrict__ s,
                     unsigned short* __restrict__ xt) {
  __shared__ float T[64][68];
  int h = blockIdx.x, b = blockIdx.y;
  const float* xp = x + (size_t)b * 512 * 4096 + h * 64;
  unsigned short* xo = xt + ((size_t)(b * 64 + h) * 64) * 512;
  int t = threadIdx.x;
  for (int ic0 = 0; ic0 < 512; ic0 += 64) {
    // load 64 ic-rows x 64 w as float4 (coalesced 16B/lane), scale by s
#pragma unroll
    for (int k = 0; k < 4; ++k) {
      int idx = t + k * 256;          // 1024 float4s
      int icl = idx >> 4, c4 = idx & 15;
      int ic = ic0 + icl;
      float4 v = *(const float4*)&xp[(size_t)ic * 4096 + c4 * 4];
      float sc = s[b * 512 + ic];
      v.x *= sc; v.y *= sc; v.z *= sc; v.w *= sc;
      *(float4*)&T[icl][c4 * 4] = v;
    }
    __syncthreads();
    // transpose out: [w][ic] with 8-ch bf16 packs
#pragma unroll
    for (int c = t; c < 512; c += 256) {   // 64 w * 8 groups of 8 ch
      int wv = c >> 3, ig = (c & 7) * 8;
      unsigned p0 = (unsigned)f2bf(T[ig + 0][wv]) | ((unsigned)f2bf(T[ig + 1][wv]) << 16);
      unsigned p1 = (unsigned)f2bf(T[ig + 2][wv]) | ((unsigned)f2bf(T[ig + 3][wv]) << 16);
      unsigned p2 = (unsigned)f2bf(T[ig + 4][wv]) | ((unsigned)f2bf(T[ig + 5][wv]) << 16);
      unsigned p3 = (unsigned)f2bf(T[ig + 6][wv]) | ((unsigned)f2bf(T[ig + 7][wv]) << 16);
      uint4 pk = {p0, p1, p2, p3};
      *(uint4*)&xo[(size_t)wv * 512 + ic0 + ig] = pk;
    }
    __syncthreads();
  }
}

// ---------- kernel 5: the conv (implicit GEMM, MFMA bf16) ----------
// grid (16 h-tiles, 4 o-tiles, 16 b); block 256 = 4 waves.
// Tile: 128 o x (4 rows x 64 cols). Wave: 128 o x 1 row; 8x4 accs of 16x16.
// LDS-read-BW optimized: 12 ds_read_b128 per 32 MFMAs (42.7 FLOP/LDS-byte).
__global__ __launch_bounds__(256, 2)
void k_conv(const unsigned short* __restrict__ xt, const unsigned short* __restrict__ wt,
            const float* __restrict__ dscale, float* __restrict__ out) {
  __shared__ short Xs[6 * 66 * 32];   // [row(6: 4+2 halo)][col(pad+64+pad)][ic32]
  __shared__ short Ws[3 * 128 * 32];  // [kw][o128][ic32]

  const int b  = blockIdx.z;
  const int o0 = blockIdx.y * 128;
  const int h0 = blockIdx.x * 4;
  const int t = threadIdx.x;
  const int wave = t >> 6, lane = t & 63;
  const int q = lane >> 4, l16 = lane & 15;

  f32x4 acc[8][4];
#pragma unroll
  for (int i = 0; i < 8; ++i)
#pragma unroll
    for (int j = 0; j < 4; ++j) acc[i][j] = (f32x4){0.f, 0.f, 0.f, 0.f};

  // zero the halo columns (col 0 and 65) of all 6 rows; never overwritten by staging
  if (t < 192) {
    int r = t >> 5, rem = t & 31;
    int col = (rem >> 4) * 65, ch2 = (rem & 15) * 2;
    *(int*)&Xs[(r * 66 + col) * 32 + ch2] = 0;
  }

  // X staging: 24 chunks of 1KB (6 rows x 4 col-quarters); 6 per wave
  int xrowi[6]; bool xval[6];
#pragma unroll
  for (int j = 0; j < 6; ++j) {
    int c = wave * 6 + j;
    int row = c >> 2;
    int hg = h0 - 1 + row;
    xval[j] = (hg >= 0) && (hg < 64);
    xrowi[j] = c;
    (void)xrowi;
  }

  for (int ic0 = 0; ic0 < 512; ic0 += 32) {
    __syncthreads();
    // ---- stage X: 6 rows x 64 cols x 32 ch (24 KB); 6 x 1KB chunks per wave
#pragma unroll
    for (int j = 0; j < 6; ++j) {
      int c = wave * 6 + j;
      int row = c >> 2, q16 = c & 3;
      int hg = h0 - 1 + row;
      short* dst = &Xs[(row * 66 + 1 + q16 * 16) * 32];
      if (xval[j]) {
        const unsigned short* src =
            xt + ((size_t)((b * 64 + hg) * 64) + q16 * 16 + (lane >> 2)) * 512 + ic0 + (lane & 3) * 8;
        async16(src, dst);
      } else {
        *(int4*)&dst[lane * 8] = (int4){0, 0, 0, 0};
      }
    }
#pragma unroll
    for (int kh = 0; kh < 3; ++kh) {
      if (kh) __syncthreads();
      // ---- stage W for this kh: 3 kw x 128 o x 32 ic (24 KB); 6 x 1KB per wave
#pragma unroll
      for (int j = 0; j < 6; ++j) {
        int ci = wave * 6 + j;
        int kw = ci >> 3, oo = ((ci & 7) << 4) + (lane >> 2);
        async16(wt + (((size_t)(kh * 3 + kw) * 512 + o0 + oo) * 512 + ic0 + (lane & 3) * 8),
                &Ws[ci * 512]);
      }
      __syncthreads();
      // ---- compute: this wave's row = h0+wave, staged X row = wave+kh
      const short* xbase = &Xs[(wave + kh) * 66 * 32 + q * 8];
#pragma unroll
      for (int kw = 0; kw < 3; ++kw) {
        bf16x8 bfr[4];
#pragma unroll
        for (int ni = 0; ni < 4; ++ni)
          bfr[ni] = *(const bf16x8*)&xbase[(ni * 16 + l16 + kw) * 32];
#pragma unroll
        for (int mi = 0; mi < 8; ++mi) {
          bf16x8 af = *(const bf16x8*)&Ws[(kw * 128 + mi * 16 + l16) * 32 + q * 8];
#pragma unroll
          for (int ni = 0; ni < 4; ++ni)
            acc[mi][ni] = __builtin_amdgcn_mfma_f32_16x16x32_bf16(af, bfr[ni], acc[mi][ni], 0, 0, 0);
        }
      }
    }
  }

  // ---- epilogue: D[row=q*4+r][col=l16] per 16x16 frag; scale by dscale[b,o]
  const int h = h0 + wave;
#pragma unroll
  for (int mi = 0; mi < 8; ++mi) {
#pragma unroll
    for (int r = 0; r < 4; ++r) {
      int o_l = mi * 16 + q * 4 + r;
      float ds = dscale[b * 512 + o0 + o_l];
      float* orow = out + ((size_t)(b * 512 + o0 + o_l) * 64 + h) * 64;
#pragma unroll
      for (int ni = 0; ni < 4; ++ni)
        orow[ni * 16 + l16] = acc[mi][ni][r] * ds;
    }
  }
}

extern "C" void kernel_launch(void* const* d_in, const int* in_sizes, int n_in,
                              void* d_out, int out_size, void* d_ws, size_t ws_size,
                              hipStream_t stream) {
  const float* x      = (const float*)d_in[0];  // (16,512,64,64)
  const float* style  = (const float*)d_in[1];  // (16,512)
  const float* weight = (const float*)d_in[2];  // (1,512,512,3,3)
  const float* mw     = (const float*)d_in[3];  // (512,512)
  const float* mb     = (const float*)d_in[4];  // (512,)
  float* out = (float*)d_out;

  // workspace layout
  float* s      = (float*)d_ws;                       // 8192 f32
  float* dscale = s + 8192;                           // 8192 f32
  float* wsq    = dscale + 8192;                      // 262144 f32
  unsigned short* wt = (unsigned short*)(wsq + 262144);  // 9*512*512 bf16 = 4.5 MiB
  unsigned short* xt = wt + 9 * 512 * 512;            // 16*64*64*512 bf16 = 64 MiB

  k_style<<<32, 256, 0, stream>>>(style, mw, mb, s);
  k_prepw<<<1024, 256, 0, stream>>>(weight, wsq, wt);
  k_dscale<<<32, 256, 0, stream>>>(s, wsq, dscale);
  k_xt<<<dim3(64, 16), 256, 0, stream>>>(x, s, xt);
  k_conv<<<dim3(16, 4, 16), 256, 0, stream>>>(xt, wt, dscale, out);
}